// Round 6
// baseline (798.982 us; speedup 1.0000x reference)
//
#include <hip/hip_runtime.h>
#include <hip/hip_bf16.h>

#define NEL 1024
#define NUP 512
#define DEMB 256
#define WID 64

typedef __attribute__((ext_vector_type(8))) short bf16x8;
typedef __attribute__((ext_vector_type(4))) float f32x4;
typedef __attribute__((ext_vector_type(16))) float f32x16;

#define CTANH 2.8853900817779268f   // 2*log2(e): tanh(a)=1-2/(exp2(CTANH*a)+1)
#define LOG2E 1.4426950408889634f
#define LN2   0.6931471805599453f

#define NEMB_BLK 256                 // embed blocks come FIRST in the grid
#define NPAIR_BLK 4096               // 256 pairs per block

// ws float layout:
//  [0..1023]    : 64 spread accumulation buckets (stride 16)
//  [1024,1025]  : J0, J1
//  [2048+s*1024]: per-set: w0t[256] (W0^T*CTANH), +256 b0p[64]*CTANH,
//                 +320 b1p[64]*CTANH, +384 w2p[64]*scale, +448 {A, log2e/F}
//  float idx 4096 onward, as shorts: w1t_s[4608], w1t_d[4608]  ([n][72] bf16, *CTANH)

__device__ __forceinline__ float tanh_pre(float y) {
    // y = CTANH * a ; returns tanh(a). Saturates correctly, NaN-free for finite y.
    float e = __builtin_amdgcn_exp2f(y);
    return fmaf(-2.0f, __builtin_amdgcn_rcpf(e + 1.0f), 1.0f);
}

__device__ __forceinline__ short f2bf(float x) {
    unsigned u = __builtin_bit_cast(unsigned, x);
    u += 0x7FFFu + ((u >> 16) & 1u);
    return (short)(u >> 16);
}

__device__ __forceinline__ float softplus_f(float x) {
    return fmaxf(x, 0.0f) + __logf(1.0f + __expf(-fabsf(x)));
}

__global__ __launch_bounds__(256) void prep_kernel(
    const float* __restrict__ W0s, const float* __restrict__ b0s,
    const float* __restrict__ W1s, const float* __restrict__ b1s, const float* __restrict__ W2s,
    const float* __restrict__ W0d, const float* __restrict__ b0d,
    const float* __restrict__ W1d, const float* __restrict__ b1d, const float* __restrict__ W2d,
    const float* __restrict__ As, const float* __restrict__ Ad,
    const float* __restrict__ ss, const float* __restrict__ sd,
    float* __restrict__ wsf)
{
    short* w1ws = (short*)(wsf + 4096);
    const int b = blockIdx.x, tid = threadIdx.x;
    if (b < 16) {
        const int s = b >> 3, c = b & 7;
        const float* W1 = s ? W1d : W1s;
        #pragma unroll
        for (int it = 0; it < 2; ++it) {
            const int local = (c << 9) + (it << 8) + tid;   // 512 entries per block
            const int n = local >> 6, k = local & 63;
            w1ws[s * 4608 + n * 72 + k] = f2bf(CTANH * W1[k * 64 + n]);
        }
    } else {
        for (int idx = tid; idx < 1026; idx += 256) wsf[idx] = 0.0f;
        #pragma unroll
        for (int s = 0; s < 2; ++s) {
            const float* W0 = s ? W0d : W0s;
            const float* b0 = s ? b0d : b0s;
            const float* b1 = s ? b1d : b1s;
            const float* w2 = s ? W2d : W2s;
            const float scl = (s ? sd : ss)[0];
            const int base = 2048 + s * 1024;
            { const int k = tid >> 6, n = tid & 63; wsf[base + n * 4 + k] = CTANH * W0[tid]; }
            if (tid < 64) {
                wsf[base + 256 + tid] = CTANH * b0[tid];
                wsf[base + 320 + tid] = CTANH * b1[tid];
                wsf[base + 384 + tid] = scl * w2[tid];
            }
            if (tid == 0) {
                const float A = softplus_f((s ? Ad : As)[0]);
                wsf[base + 448] = A;
                wsf[base + 449] = LOG2E * __builtin_amdgcn_rsqf(2.0f * A);  // log2e/F
            }
        }
    }
}

// Blocks [0,256): embedding MLP (4 rows/block) — FIRST so their latency-bound
//   waves overlap with pair blocks instead of running as an idle tail.
// Blocks [256,4352): 256 pairs each (wave = 32 pairs x 2 j-tiles, MFMA 32x32x16).
__global__ __launch_bounds__(256, 8) void pair_kernel(
    const float* __restrict__ electrons,
    const float* __restrict__ wsf,
    float* __restrict__ accum,
    const float* __restrict__ emb,
    const float* __restrict__ We0, const float* __restrict__ be0,
    const float* __restrict__ We1, const float* __restrict__ be1,
    const float* __restrict__ We2, const float* __restrict__ be2,
    const float* __restrict__ mlp_scale, const float* __restrict__ log_bias)
{
    __shared__ __align__(16) char smem[11264];
    const int tid = threadIdx.x, bidx = blockIdx.x;
    const int lane = tid & 63, wv = tid >> 6;

    if (bidx < NEMB_BLK) {
        // ---------------- embedding path ----------------
        float* xs  = (float*)smem;          // [4][256]
        float* h0s = (float*)(smem + 4096); // [4][64]
        const int row = (bidx << 2) + wv;

        for (int k = lane; k < DEMB; k += 64) xs[(wv << 8) + k] = emb[row * DEMB + k];
        __syncthreads();

        float a0 = 0, a1 = 0, a2 = 0, a3 = 0;
        #pragma unroll 4
        for (int k = 0; k < DEMB; k += 4) {
            a0 = fmaf(xs[(wv << 8) + k],     We0[(k)     * WID + lane], a0);
            a1 = fmaf(xs[(wv << 8) + k + 1], We0[(k + 1) * WID + lane], a1);
            a2 = fmaf(xs[(wv << 8) + k + 2], We0[(k + 2) * WID + lane], a2);
            a3 = fmaf(xs[(wv << 8) + k + 3], We0[(k + 3) * WID + lane], a3);
        }
        h0s[(wv << 6) + lane] = tanh_pre(CTANH * ((a0 + a1) + (a2 + a3) + be0[lane]));
        __syncthreads();

        float c0 = 0, c1 = 0;
        #pragma unroll 4
        for (int k = 0; k < WID; k += 2) {
            c0 = fmaf(h0s[(wv << 6) + k],     We1[(k)     * WID + lane], c0);
            c1 = fmaf(h0s[(wv << 6) + k + 1], We1[(k + 1) * WID + lane], c1);
        }
        const float h1 = tanh_pre(CTANH * (c0 + c1 + be1[lane]));

        float p0 = h1 * We2[2 * lane], p1 = h1 * We2[2 * lane + 1];
        #pragma unroll
        for (int off = 32; off; off >>= 1) {
            p0 += __shfl_down(p0, off);
            p1 += __shfl_down(p1, off);
        }
        if (lane == 0) {
            atomicAdd(&accum[1024], (p0 + be2[0]) * mlp_scale[0]);
            atomicAdd(&accum[1025], (p1 + be2[1]) * mlp_scale[1] + log_bias[0]);
        }
        return;
    }

    // ---------------- pair path ----------------
    short* w1t  = (short*)smem;            // [64][72] bf16, prescaled
    float* w0t  = (float*)(smem + 9216);   // [64][4]  f32, prescaled
    float* b0sh = (float*)(smem + 10240);  // [64]
    float* b1sh = (float*)(smem + 10496);  // [64]
    float* w2sh = (float*)(smem + 10752);  // [64] (pre-multiplied by scale)
    float* wsum = (float*)(smem + 11008);  // [4]

    const int pb = bidx - NEMB_BLK;
    const int i  = pb >> 2;
    const int jb = (pb & 3) << 8;          // 256 j per block (spin-uniform: 256|512)
    const int sset = ((i < NUP) == (jb < NUP)) ? 0 : 1;
    const float* wbase = wsf + 2048 + sset * 1024;
    const short* w1g   = (const short*)(wsf + 4096) + sset * 4608;

    {
        const float4* src = (const float4*)w1g;
        float4* dst = (float4*)w1t;
        for (int idx = tid; idx < 576; idx += 256) dst[idx] = src[idx];
        if (tid < 64) {
            ((float4*)w0t)[tid] = ((const float4*)wbase)[tid];
            b0sh[tid] = wbase[256 + tid];
            b1sh[tid] = wbase[320 + tid];
            w2sh[tid] = wbase[384 + tid];
        }
    }
    const float A     = wbase[448];
    const float invF2 = wbase[449];

    const int hi = lane >> 5, p32 = lane & 31;
    const float eix = electrons[3 * i], eiy = electrons[3 * i + 1], eiz = electrons[3 * i + 2];

    __syncthreads();

    float thread_sum = 0.0f;

    #pragma unroll 1
    for (int jt = 0; jt < 2; ++jt) {
        const int j = jb + (((wv << 1) + jt) << 5) + p32;
        const bool diag = (j == i);

        // ---- features (sanitized on diagonal) ----
        float dx = eix - electrons[3 * j];
        float dy = eiy - electrons[3 * j + 1];
        float dz = eiz - electrons[3 * j + 2];
        if (diag) { dx = 0.0f; dy = 0.0f; dz = 0.0f; }
        float r2 = fmaf(dx, dx, fmaf(dy, dy, dz * dz));
        if (diag) r2 = 1.0f;
        const float rr    = __builtin_amdgcn_sqrtf(r2);
        const float inv_r = __builtin_amdgcn_rcpf(rr);
        const float l1p   = __builtin_amdgcn_logf(1.0f + rr) * LN2;
        const float gf    = l1p * inv_r;
        const float f0 = dx * gf, f1 = dy * gf, f2v = dz * gf;
        const float f3 = diag ? 0.0f : l1p;
        const float cusp = (hi == 0 && !diag)
            ? A * (__builtin_amdgcn_exp2f(-rr * invF2) - 1.0f) * inv_r : 0.0f;

        // ---- layer 1 (VALU) straight into B-fragment layout ----
        bf16x8 afr[4];
        #pragma unroll
        for (int kc = 0; kc < 4; ++kc) {
            #pragma unroll
            for (int e = 0; e < 8; ++e) {
                const int n = (kc << 4) + (hi << 3) + e;
                f32x4 w = *(const f32x4*)&w0t[n << 2];
                float y = fmaf(f3, w[3], fmaf(f2v, w[2], fmaf(f1, w[1], fmaf(f0, w[0], b0sh[n]))));
                afr[kc][e] = __bfloat16_as_ushort(__float2bfloat16(tanh_pre(y)));
            }
        }

        // ---- layer 2 (MFMA 32x32x16), C preloaded with prescaled b1 ----
        f32x16 acc0, acc1;
        #pragma unroll
        for (int q = 0; q < 4; ++q) {
            const f32x4 v0 = *(const f32x4*)&b1sh[(q << 3) + (hi << 2)];
            const f32x4 v1 = *(const f32x4*)&b1sh[32 + (q << 3) + (hi << 2)];
            #pragma unroll
            for (int e = 0; e < 4; ++e) { acc0[(q << 2) + e] = v0[e]; acc1[(q << 2) + e] = v1[e]; }
        }
        const short* w1r0 = &w1t[p32 * 72 + (hi << 3)];
        const short* w1r1 = &w1t[(32 + p32) * 72 + (hi << 3)];
        #pragma unroll
        for (int kc = 0; kc < 4; ++kc) {
            bf16x8 wa0 = *(const bf16x8*)(w1r0 + (kc << 4));
            bf16x8 wa1 = *(const bf16x8*)(w1r1 + (kc << 4));
            acc0 = __builtin_amdgcn_mfma_f32_32x32x16_bf16(wa0, afr[kc], acc0, 0, 0, 0);
            acc1 = __builtin_amdgcn_mfma_f32_32x32x16_bf16(wa1, afr[kc], acc1, 0, 0, 0);
        }

        // ---- layer 3 epilogue: lane-local (col = own pair); w2 includes scale ----
        float s = 0.0f;
        #pragma unroll
        for (int q = 0; q < 4; ++q) {
            const f32x4 u0 = *(const f32x4*)&w2sh[(q << 3) + (hi << 2)];
            const f32x4 u1 = *(const f32x4*)&w2sh[32 + (q << 3) + (hi << 2)];
            #pragma unroll
            for (int e = 0; e < 4; ++e) {
                s = fmaf(tanh_pre(acc0[(q << 2) + e]), u0[e], s);
                s = fmaf(tanh_pre(acc1[(q << 2) + e]), u1[e], s);
            }
        }
        if (diag) s = 0.0f;
        thread_sum += s + cusp;
    }

    // ---- reduce: wave -> block -> spread atomic bucket ----
    #pragma unroll
    for (int off = 32; off; off >>= 1) thread_sum += __shfl_down(thread_sum, off);
    if (lane == 0) wsum[wv] = thread_sum;
    __syncthreads();
    if (tid == 0)
        atomicAdd(&accum[(bidx & 63) << 4], wsum[0] + wsum[1] + wsum[2] + wsum[3]);
}

__global__ __launch_bounds__(64) void final_kernel(const float* __restrict__ accum,
                                                   float* __restrict__ out)
{
    const int lane = threadIdx.x;
    float v = accum[lane << 4];
    #pragma unroll
    for (int off = 32; off; off >>= 1) v += __shfl_down(v, off);
    if (lane == 0) {
        const float J0 = accum[1024];
        const float J1 = accum[1025];
        const float sign = (J1 > 0.0f) ? 1.0f : ((J1 < 0.0f) ? -1.0f : 0.0f);
        out[0] = sign;
        out[1] = v + J0 + logf(fabsf(J1));
    }
}

extern "C" void kernel_launch(void* const* d_in, const int* in_sizes, int n_in,
                              void* d_out, int out_size, void* d_ws, size_t ws_size,
                              hipStream_t stream) {
    const float* electrons  = (const float*)d_in[0];
    const float* embeddings = (const float*)d_in[1];
    const float* A_same     = (const float*)d_in[2];
    const float* A_diff     = (const float*)d_in[3];
    const float* Ws0_same   = (const float*)d_in[4];
    const float* bs0_same   = (const float*)d_in[5];
    const float* Ws1_same   = (const float*)d_in[6];
    const float* bs1_same   = (const float*)d_in[7];
    const float* Ws2_same   = (const float*)d_in[8];
    const float* Ws0_diff   = (const float*)d_in[9];
    const float* bs0_diff   = (const float*)d_in[10];
    const float* Ws1_diff   = (const float*)d_in[11];
    const float* bs1_diff   = (const float*)d_in[12];
    const float* Ws2_diff   = (const float*)d_in[13];
    const float* scale_same = (const float*)d_in[14];
    const float* scale_diff = (const float*)d_in[15];
    const float* We0        = (const float*)d_in[16];
    const float* be0        = (const float*)d_in[17];
    const float* We1        = (const float*)d_in[18];
    const float* be1        = (const float*)d_in[19];
    const float* We2        = (const float*)d_in[20];
    const float* be2        = (const float*)d_in[21];
    const float* mlp_scale  = (const float*)d_in[22];
    const float* log_bias   = (const float*)d_in[23];

    float* out = (float*)d_out;
    float* wsf = (float*)d_ws;

    hipLaunchKernelGGL(prep_kernel, dim3(17), dim3(256), 0, stream,
        Ws0_same, bs0_same, Ws1_same, bs1_same, Ws2_same,
        Ws0_diff, bs0_diff, Ws1_diff, bs1_diff, Ws2_diff,
        A_same, A_diff, scale_same, scale_diff, wsf);

    hipLaunchKernelGGL(pair_kernel, dim3(NEMB_BLK + NPAIR_BLK), dim3(256), 0, stream,
        electrons, wsf, wsf,
        embeddings, We0, be0, We1, be1, We2, be2, mlp_scale, log_bias);

    hipLaunchKernelGGL(final_kernel, dim3(1), dim3(64), 0, stream, wsf, out);
}

// Round 7
// 79.698 us; speedup vs baseline: 10.0252x; 10.0252x over previous
//
#include <hip/hip_runtime.h>
#include <hip/hip_bf16.h>

#define NEL 1024
#define NUP 512
#define DEMB 256
#define WID 64

typedef __attribute__((ext_vector_type(8))) short bf16x8;
typedef __attribute__((ext_vector_type(4))) float f32x4;
typedef __attribute__((ext_vector_type(16))) float f32x16;

#define CTANH 2.8853900817779268f   // 2*log2(e): tanh(a)=1-2/(exp2(CTANH*a)+1)
#define LOG2E 1.4426950408889634f
#define LN2   0.6931471805599453f

// ws float layout:
//  [0..1023]    : 64 spread accumulation buckets (stride 16)
//  [1024,1025]  : J0, J1
//  [2048+s*1024]: per-set: w0t[256] (W0^T*CTANH), +256 b0p[64]*CTANH,
//                 +320 b1p[64]*CTANH, +384 w2p[64]*scale, +448 {A, log2e/F}
//  float idx 4096 onward, as shorts: w1t_s[4608], w1t_d[4608]  ([n][72] bf16, *CTANH)

__device__ __forceinline__ float tanh_pre(float y) {
    // y = CTANH * a ; returns tanh(a). Saturates correctly, NaN-free for finite y.
    float e = __builtin_amdgcn_exp2f(y);
    return fmaf(-2.0f, __builtin_amdgcn_rcpf(e + 1.0f), 1.0f);
}

__device__ __forceinline__ short f2bf(float x) {
    unsigned u = __builtin_bit_cast(unsigned, x);
    u += 0x7FFFu + ((u >> 16) & 1u);
    return (short)(u >> 16);
}

__device__ __forceinline__ float softplus_f(float x) {
    return fmaxf(x, 0.0f) + __logf(1.0f + __expf(-fabsf(x)));
}

__global__ __launch_bounds__(256) void prep_kernel(
    const float* __restrict__ W0s, const float* __restrict__ b0s,
    const float* __restrict__ W1s, const float* __restrict__ b1s, const float* __restrict__ W2s,
    const float* __restrict__ W0d, const float* __restrict__ b0d,
    const float* __restrict__ W1d, const float* __restrict__ b1d, const float* __restrict__ W2d,
    const float* __restrict__ As, const float* __restrict__ Ad,
    const float* __restrict__ ss, const float* __restrict__ sd,
    float* __restrict__ wsf)
{
    short* w1ws = (short*)(wsf + 4096);
    const int b = blockIdx.x, tid = threadIdx.x;
    if (b < 16) {
        const int s = b >> 3, c = b & 7;
        const float* W1 = s ? W1d : W1s;
        #pragma unroll
        for (int it = 0; it < 2; ++it) {
            const int local = (c << 9) + (it << 8) + tid;   // 512 entries per block
            const int n = local >> 6, k = local & 63;
            w1ws[s * 4608 + n * 72 + k] = f2bf(CTANH * W1[k * 64 + n]);
        }
    } else {
        for (int idx = tid; idx < 1026; idx += 256) wsf[idx] = 0.0f;
        #pragma unroll
        for (int s = 0; s < 2; ++s) {
            const float* W0 = s ? W0d : W0s;
            const float* b0 = s ? b0d : b0s;
            const float* b1 = s ? b1d : b1s;
            const float* w2 = s ? W2d : W2s;
            const float scl = (s ? sd : ss)[0];
            const int base = 2048 + s * 1024;
            { const int k = tid >> 6, n = tid & 63; wsf[base + n * 4 + k] = CTANH * W0[tid]; }
            if (tid < 64) {
                wsf[base + 256 + tid] = CTANH * b0[tid];
                wsf[base + 320 + tid] = CTANH * b1[tid];
                wsf[base + 384 + tid] = scl * w2[tid];
            }
            if (tid == 0) {
                const float A = softplus_f((s ? Ad : As)[0]);
                wsf[base + 448] = A;
                wsf[base + 449] = LOG2E * __builtin_amdgcn_rsqf(2.0f * A);  // log2e/F
            }
        }
    }
}

// 128 pairs per block (wave = 32 pairs, MFMA 32x32x16). Straight-line body —
// no rolled loops around the MFMA accumulators (R6 lesson: spill disaster).
__global__ __launch_bounds__(256, 2) void pair_kernel(
    const float* __restrict__ electrons,
    const float* __restrict__ wsf,
    float* __restrict__ accum)
{
    __shared__ __align__(16) short w1t[4608];   // [n][72] bf16 prescaled
    __shared__ __align__(16) float w0t[256];    // [n][4]  f32 prescaled
    __shared__ float b0sh[64], b1sh[64], w2sh[64];
    __shared__ float wsum[4];

    const int tid  = threadIdx.x;
    const int bidx = blockIdx.x;
    const int i  = bidx >> 3;
    const int jb = (bidx & 7) << 7;            // 128 j per block (spin-uniform)
    const int sset = ((i < NUP) == (jb < NUP)) ? 0 : 1;
    const float* wbase = wsf + 2048 + sset * 1024;
    const short* w1g   = (const short*)(wsf + 4096) + sset * 4608;

    // pure vector-copy staging (preconverted in prep)
    {
        const float4* src = (const float4*)w1g;
        float4* dst = (float4*)w1t;
        for (int idx = tid; idx < 576; idx += 256) dst[idx] = src[idx];
        if (tid < 64) {
            ((float4*)w0t)[tid] = ((const float4*)wbase)[tid];
            b0sh[tid] = wbase[256 + tid];
            b1sh[tid] = wbase[320 + tid];
            w2sh[tid] = wbase[384 + tid];
        }
    }
    const float A     = wbase[448];
    const float invF2 = wbase[449];
    __syncthreads();

    const int lane = tid & 63, wv = tid >> 6;
    const int hi = lane >> 5, p32 = lane & 31;
    const int j = jb + (wv << 5) + p32;
    const bool diag = (j == i);

    // ---- features (sanitized on diagonal) ----
    const float eix = electrons[3 * i], eiy = electrons[3 * i + 1], eiz = electrons[3 * i + 2];
    float dx = eix - electrons[3 * j];
    float dy = eiy - electrons[3 * j + 1];
    float dz = eiz - electrons[3 * j + 2];
    if (diag) { dx = 0.0f; dy = 0.0f; dz = 0.0f; }
    float r2 = fmaf(dx, dx, fmaf(dy, dy, dz * dz));
    if (diag) r2 = 1.0f;
    const float rr    = __builtin_amdgcn_sqrtf(r2);
    const float inv_r = __builtin_amdgcn_rcpf(rr);
    const float l1p   = __builtin_amdgcn_logf(1.0f + rr) * LN2;
    const float gf    = l1p * inv_r;
    const float f0 = dx * gf, f1 = dy * gf, f2v = dz * gf;
    const float f3 = diag ? 0.0f : l1p;
    const float cusp = (hi == 0 && !diag)
        ? A * (__builtin_amdgcn_exp2f(-rr * invF2) - 1.0f) * inv_r : 0.0f;

    // ---- layer 1 (VALU) straight into B-fragment layout ----
    // lane owns pair p32; k-elem e of chunk kc = neuron n = 16*kc + 8*hi + e
    bf16x8 afr[4];
    #pragma unroll
    for (int kc = 0; kc < 4; ++kc) {
        #pragma unroll
        for (int e = 0; e < 8; ++e) {
            const int n = (kc << 4) + (hi << 3) + e;
            f32x4 w = *(const f32x4*)&w0t[n << 2];
            float y = fmaf(f3, w[3], fmaf(f2v, w[2], fmaf(f1, w[1], fmaf(f0, w[0], b0sh[n]))));
            afr[kc][e] = __bfloat16_as_ushort(__float2bfloat16(tanh_pre(y)));
        }
    }

    // ---- layer 2 (MFMA 32x32x16), C preloaded with prescaled b1 ----
    f32x16 acc0, acc1;
    #pragma unroll
    for (int q = 0; q < 4; ++q) {
        const f32x4 v0 = *(const f32x4*)&b1sh[(q << 3) + (hi << 2)];
        const f32x4 v1 = *(const f32x4*)&b1sh[32 + (q << 3) + (hi << 2)];
        #pragma unroll
        for (int e = 0; e < 4; ++e) { acc0[(q << 2) + e] = v0[e]; acc1[(q << 2) + e] = v1[e]; }
    }
    const short* w1r0 = &w1t[p32 * 72 + (hi << 3)];
    const short* w1r1 = &w1t[(32 + p32) * 72 + (hi << 3)];
    #pragma unroll
    for (int kc = 0; kc < 4; ++kc) {
        bf16x8 wa0 = *(const bf16x8*)(w1r0 + (kc << 4));
        bf16x8 wa1 = *(const bf16x8*)(w1r1 + (kc << 4));
        acc0 = __builtin_amdgcn_mfma_f32_32x32x16_bf16(wa0, afr[kc], acc0, 0, 0, 0);
        acc1 = __builtin_amdgcn_mfma_f32_32x32x16_bf16(wa1, afr[kc], acc1, 0, 0, 0);
    }

    // ---- layer 3 epilogue: lane-local (col = own pair); w2 includes scale ----
    float s = 0.0f;
    #pragma unroll
    for (int q = 0; q < 4; ++q) {
        const f32x4 u0 = *(const f32x4*)&w2sh[(q << 3) + (hi << 2)];
        const f32x4 u1 = *(const f32x4*)&w2sh[32 + (q << 3) + (hi << 2)];
        #pragma unroll
        for (int e = 0; e < 4; ++e) {
            s = fmaf(tanh_pre(acc0[(q << 2) + e]), u0[e], s);
            s = fmaf(tanh_pre(acc1[(q << 2) + e]), u1[e], s);
        }
    }
    if (diag) s = 0.0f;
    float partial = s + cusp;

    #pragma unroll
    for (int off = 32; off; off >>= 1) partial += __shfl_down(partial, off);
    if (lane == 0) wsum[wv] = partial;
    __syncthreads();
    if (tid == 0)
        atomicAdd(&accum[(bidx & 63) << 4], wsum[0] + wsum[1] + wsum[2] + wsum[3]);
}

// One row per wave; all LDS strictly wave-private -> no barriers.
// 8 independent layer-1 accumulators break the k=256 load-latency chain.
__global__ __launch_bounds__(256) void embed_kernel(
    const float* __restrict__ emb,
    const float* __restrict__ We0, const float* __restrict__ be0,
    const float* __restrict__ We1, const float* __restrict__ be1,
    const float* __restrict__ We2, const float* __restrict__ be2,
    const float* __restrict__ mlp_scale, const float* __restrict__ log_bias,
    float* __restrict__ accum)
{
    __shared__ float xs[4][DEMB];
    __shared__ float h0s[4][WID];
    const int tid = threadIdx.x, wv = tid >> 6, lane = tid & 63;
    const int row = (blockIdx.x << 2) + wv;

    for (int k = lane; k < DEMB; k += 64) xs[wv][k] = emb[row * DEMB + k];

    float a[8];
    #pragma unroll
    for (int t = 0; t < 8; ++t) a[t] = 0.0f;
    #pragma unroll 1
    for (int k = 0; k < DEMB; k += 8) {
        #pragma unroll
        for (int t = 0; t < 8; ++t)
            a[t] = fmaf(xs[wv][k + t], We0[(k + t) * WID + lane], a[t]);
    }
    const float asum = ((a[0] + a[1]) + (a[2] + a[3])) + ((a[4] + a[5]) + (a[6] + a[7]));
    h0s[wv][lane] = tanh_pre(CTANH * (asum + be0[lane]));

    float c0 = 0, c1 = 0, c2 = 0, c3 = 0;
    #pragma unroll 4
    for (int k = 0; k < WID; k += 4) {
        c0 = fmaf(h0s[wv][k],     We1[(k)     * WID + lane], c0);
        c1 = fmaf(h0s[wv][k + 1], We1[(k + 1) * WID + lane], c1);
        c2 = fmaf(h0s[wv][k + 2], We1[(k + 2) * WID + lane], c2);
        c3 = fmaf(h0s[wv][k + 3], We1[(k + 3) * WID + lane], c3);
    }
    const float h1 = tanh_pre(CTANH * ((c0 + c1) + (c2 + c3) + be1[lane]));

    float p0 = h1 * We2[2 * lane], p1 = h1 * We2[2 * lane + 1];
    #pragma unroll
    for (int off = 32; off; off >>= 1) {
        p0 += __shfl_down(p0, off);
        p1 += __shfl_down(p1, off);
    }
    if (lane == 0) {
        atomicAdd(&accum[1024], (p0 + be2[0]) * mlp_scale[0]);
        atomicAdd(&accum[1025], (p1 + be2[1]) * mlp_scale[1] + log_bias[0]);
    }
}

__global__ __launch_bounds__(64) void final_kernel(const float* __restrict__ accum,
                                                   float* __restrict__ out)
{
    const int lane = threadIdx.x;
    float v = accum[lane << 4];
    #pragma unroll
    for (int off = 32; off; off >>= 1) v += __shfl_down(v, off);
    if (lane == 0) {
        const float J0 = accum[1024];
        const float J1 = accum[1025];
        const float sign = (J1 > 0.0f) ? 1.0f : ((J1 < 0.0f) ? -1.0f : 0.0f);
        out[0] = sign;
        out[1] = v + J0 + logf(fabsf(J1));
    }
}

extern "C" void kernel_launch(void* const* d_in, const int* in_sizes, int n_in,
                              void* d_out, int out_size, void* d_ws, size_t ws_size,
                              hipStream_t stream) {
    const float* electrons  = (const float*)d_in[0];
    const float* embeddings = (const float*)d_in[1];
    const float* A_same     = (const float*)d_in[2];
    const float* A_diff     = (const float*)d_in[3];
    const float* Ws0_same   = (const float*)d_in[4];
    const float* bs0_same   = (const float*)d_in[5];
    const float* Ws1_same   = (const float*)d_in[6];
    const float* bs1_same   = (const float*)d_in[7];
    const float* Ws2_same   = (const float*)d_in[8];
    const float* Ws0_diff   = (const float*)d_in[9];
    const float* bs0_diff   = (const float*)d_in[10];
    const float* Ws1_diff   = (const float*)d_in[11];
    const float* bs1_diff   = (const float*)d_in[12];
    const float* Ws2_diff   = (const float*)d_in[13];
    const float* scale_same = (const float*)d_in[14];
    const float* scale_diff = (const float*)d_in[15];
    const float* We0        = (const float*)d_in[16];
    const float* be0        = (const float*)d_in[17];
    const float* We1        = (const float*)d_in[18];
    const float* be1        = (const float*)d_in[19];
    const float* We2        = (const float*)d_in[20];
    const float* be2        = (const float*)d_in[21];
    const float* mlp_scale  = (const float*)d_in[22];
    const float* log_bias   = (const float*)d_in[23];

    float* out = (float*)d_out;
    float* wsf = (float*)d_ws;

    hipLaunchKernelGGL(prep_kernel, dim3(17), dim3(256), 0, stream,
        Ws0_same, bs0_same, Ws1_same, bs1_same, Ws2_same,
        Ws0_diff, bs0_diff, Ws1_diff, bs1_diff, Ws2_diff,
        A_same, A_diff, scale_same, scale_diff, wsf);

    hipLaunchKernelGGL(pair_kernel, dim3(NEL * NEL / 128), dim3(256), 0, stream,
        electrons, wsf, wsf);

    hipLaunchKernelGGL(embed_kernel, dim3(NEL / 4), dim3(256), 0, stream,
        embeddings, We0, be0, We1, be1, We2, be2, mlp_scale, log_bias, wsf);

    hipLaunchKernelGGL(final_kernel, dim3(1), dim3(64), 0, stream, wsf, out);
}

// Round 8
// 52.087 us; speedup vs baseline: 15.3394x; 1.5301x over previous
//
#include <hip/hip_runtime.h>
#include <hip/hip_bf16.h>

#define NEL 1024
#define NUP 512
#define DEMB 256
#define WID 64

typedef __attribute__((ext_vector_type(8))) short bf16x8;
typedef __attribute__((ext_vector_type(4))) float f32x4;
typedef __attribute__((ext_vector_type(16))) float f32x16;

#define CTANH 2.8853900817779268f   // 2*log2(e): tanh(a)=1-2/(exp2(CTANH*a)+1)
#define LOG2E 1.4426950408889634f
#define LN2   0.6931471805599453f

// ws float layout:
//  [0..1023]    : 64 pair buckets (stride 16)
//  [1024..2047] : 64 embed buckets: J0 at 1024+b*16, J1 at 1032+b*16
//  [2048+s*1024]: per-set: w0t[256] (W0^T*CTANH), +256 b0p[64]*CTANH,
//                 +320 b1p[64]*CTANH, +384 w2p[64]*scale, +448 {A, log2e/F}
//  float idx 4096 onward, as shorts: w1t_s[4608], w1t_d[4608]  ([n][72] bf16, *CTANH)

__device__ __forceinline__ float tanh_pre(float y) {
    // y = CTANH * a ; returns tanh(a). Saturates correctly, NaN-free for finite y.
    float e = __builtin_amdgcn_exp2f(y);
    return fmaf(-2.0f, __builtin_amdgcn_rcpf(e + 1.0f), 1.0f);
}

__device__ __forceinline__ short f2bf(float x) {
    unsigned u = __builtin_bit_cast(unsigned, x);
    u += 0x7FFFu + ((u >> 16) & 1u);
    return (short)(u >> 16);
}

__device__ __forceinline__ float softplus_f(float x) {
    return fmaxf(x, 0.0f) + __logf(1.0f + __expf(-fabsf(x)));
}

__global__ __launch_bounds__(256) void prep_kernel(
    const float* __restrict__ W0s, const float* __restrict__ b0s,
    const float* __restrict__ W1s, const float* __restrict__ b1s, const float* __restrict__ W2s,
    const float* __restrict__ W0d, const float* __restrict__ b0d,
    const float* __restrict__ W1d, const float* __restrict__ b1d, const float* __restrict__ W2d,
    const float* __restrict__ As, const float* __restrict__ Ad,
    const float* __restrict__ ss, const float* __restrict__ sd,
    float* __restrict__ wsf)
{
    short* w1ws = (short*)(wsf + 4096);
    const int b = blockIdx.x, tid = threadIdx.x;
    if (b < 16) {
        const int s = b >> 3, c = b & 7;
        const float* W1 = s ? W1d : W1s;
        #pragma unroll
        for (int it = 0; it < 2; ++it) {
            const int local = (c << 9) + (it << 8) + tid;   // 512 entries per block
            const int n = local >> 6, k = local & 63;
            w1ws[s * 4608 + n * 72 + k] = f2bf(CTANH * W1[k * 64 + n]);
        }
    } else {
        for (int idx = tid; idx < 2048; idx += 256) wsf[idx] = 0.0f;
        #pragma unroll
        for (int s = 0; s < 2; ++s) {
            const float* W0 = s ? W0d : W0s;
            const float* b0 = s ? b0d : b0s;
            const float* b1 = s ? b1d : b1s;
            const float* w2 = s ? W2d : W2s;
            const float scl = (s ? sd : ss)[0];
            const int base = 2048 + s * 1024;
            { const int k = tid >> 6, n = tid & 63; wsf[base + n * 4 + k] = CTANH * W0[tid]; }
            if (tid < 64) {
                wsf[base + 256 + tid] = CTANH * b0[tid];
                wsf[base + 320 + tid] = CTANH * b1[tid];
                wsf[base + 384 + tid] = scl * w2[tid];
            }
            if (tid == 0) {
                const float A = softplus_f((s ? Ad : As)[0]);
                wsf[base + 448] = A;
                wsf[base + 449] = LOG2E * __builtin_amdgcn_rsqf(2.0f * A);  // log2e/F
            }
        }
    }
}

// 128 pairs per block (wave = 32 pairs, MFMA 32x32x16). Straight-line body —
// no rolled loops around the MFMA accumulators (R6 lesson: spill disaster).
__global__ __launch_bounds__(256, 2) void pair_kernel(
    const float* __restrict__ electrons,
    const float* __restrict__ wsf,
    float* __restrict__ accum)
{
    __shared__ __align__(16) short w1t[4608];   // [n][72] bf16 prescaled
    __shared__ __align__(16) float w0t[256];    // [n][4]  f32 prescaled
    __shared__ float b0sh[64], b1sh[64], w2sh[64];
    __shared__ float wsum[4];

    const int tid  = threadIdx.x;
    const int bidx = blockIdx.x;
    const int i  = bidx >> 3;
    const int jb = (bidx & 7) << 7;            // 128 j per block (spin-uniform)
    const int sset = ((i < NUP) == (jb < NUP)) ? 0 : 1;
    const float* wbase = wsf + 2048 + sset * 1024;
    const short* w1g   = (const short*)(wsf + 4096) + sset * 4608;

    // pure vector-copy staging (preconverted in prep)
    {
        const float4* src = (const float4*)w1g;
        float4* dst = (float4*)w1t;
        for (int idx = tid; idx < 576; idx += 256) dst[idx] = src[idx];
        if (tid < 64) {
            ((float4*)w0t)[tid] = ((const float4*)wbase)[tid];
            b0sh[tid] = wbase[256 + tid];
            b1sh[tid] = wbase[320 + tid];
            w2sh[tid] = wbase[384 + tid];
        }
    }
    const float A     = wbase[448];
    const float invF2 = wbase[449];
    __syncthreads();

    const int lane = tid & 63, wv = tid >> 6;
    const int hi = lane >> 5, p32 = lane & 31;
    const int j = jb + (wv << 5) + p32;
    const bool diag = (j == i);

    // ---- features (sanitized on diagonal) ----
    const float eix = electrons[3 * i], eiy = electrons[3 * i + 1], eiz = electrons[3 * i + 2];
    float dx = eix - electrons[3 * j];
    float dy = eiy - electrons[3 * j + 1];
    float dz = eiz - electrons[3 * j + 2];
    if (diag) { dx = 0.0f; dy = 0.0f; dz = 0.0f; }
    float r2 = fmaf(dx, dx, fmaf(dy, dy, dz * dz));
    if (diag) r2 = 1.0f;
    const float rr    = __builtin_amdgcn_sqrtf(r2);
    const float inv_r = __builtin_amdgcn_rcpf(rr);
    const float l1p   = __builtin_amdgcn_logf(1.0f + rr) * LN2;
    const float gf    = l1p * inv_r;
    const float f0 = dx * gf, f1 = dy * gf, f2v = dz * gf;
    const float f3 = diag ? 0.0f : l1p;
    const float cusp = (hi == 0 && !diag)
        ? A * (__builtin_amdgcn_exp2f(-rr * invF2) - 1.0f) * inv_r : 0.0f;

    // ---- layer 1 (VALU) straight into B-fragment layout ----
    // lane owns pair p32; k-elem e of chunk kc = neuron n = 16*kc + 8*hi + e
    bf16x8 afr[4];
    #pragma unroll
    for (int kc = 0; kc < 4; ++kc) {
        #pragma unroll
        for (int e = 0; e < 8; ++e) {
            const int n = (kc << 4) + (hi << 3) + e;
            f32x4 w = *(const f32x4*)&w0t[n << 2];
            float y = fmaf(f3, w[3], fmaf(f2v, w[2], fmaf(f1, w[1], fmaf(f0, w[0], b0sh[n]))));
            afr[kc][e] = __bfloat16_as_ushort(__float2bfloat16(tanh_pre(y)));
        }
    }

    // ---- layer 2 (MFMA 32x32x16), C preloaded with prescaled b1 ----
    f32x16 acc0, acc1;
    #pragma unroll
    for (int q = 0; q < 4; ++q) {
        const f32x4 v0 = *(const f32x4*)&b1sh[(q << 3) + (hi << 2)];
        const f32x4 v1 = *(const f32x4*)&b1sh[32 + (q << 3) + (hi << 2)];
        #pragma unroll
        for (int e = 0; e < 4; ++e) { acc0[(q << 2) + e] = v0[e]; acc1[(q << 2) + e] = v1[e]; }
    }
    const short* w1r0 = &w1t[p32 * 72 + (hi << 3)];
    const short* w1r1 = &w1t[(32 + p32) * 72 + (hi << 3)];
    #pragma unroll
    for (int kc = 0; kc < 4; ++kc) {
        bf16x8 wa0 = *(const bf16x8*)(w1r0 + (kc << 4));
        bf16x8 wa1 = *(const bf16x8*)(w1r1 + (kc << 4));
        acc0 = __builtin_amdgcn_mfma_f32_32x32x16_bf16(wa0, afr[kc], acc0, 0, 0, 0);
        acc1 = __builtin_amdgcn_mfma_f32_32x32x16_bf16(wa1, afr[kc], acc1, 0, 0, 0);
    }

    // ---- layer 3 epilogue: lane-local (col = own pair); w2 includes scale ----
    float s = 0.0f;
    #pragma unroll
    for (int q = 0; q < 4; ++q) {
        const f32x4 u0 = *(const f32x4*)&w2sh[(q << 3) + (hi << 2)];
        const f32x4 u1 = *(const f32x4*)&w2sh[32 + (q << 3) + (hi << 2)];
        #pragma unroll
        for (int e = 0; e < 4; ++e) {
            s = fmaf(tanh_pre(acc0[(q << 2) + e]), u0[e], s);
            s = fmaf(tanh_pre(acc1[(q << 2) + e]), u1[e], s);
        }
    }
    if (diag) s = 0.0f;
    float partial = s + cusp;

    #pragma unroll
    for (int off = 32; off; off >>= 1) partial += __shfl_down(partial, off);
    if (lane == 0) wsum[wv] = partial;
    __syncthreads();
    if (tid == 0)
        atomicAdd(&accum[(bidx & 63) << 4], wsum[0] + wsum[1] + wsum[2] + wsum[3]);
}

// ONE ROW PER BLOCK (1024 blocks -> 4 blocks/CU, 16 waves/CU), split-k across
// the 4 waves. Short dependent chains; latency hidden by TLP. (R7 lesson:
// 256 blocks x serial-k = 1 wave/SIMD latency disaster.)
__global__ __launch_bounds__(256) void embed_kernel(
    const float* __restrict__ emb,
    const float* __restrict__ We0, const float* __restrict__ be0,
    const float* __restrict__ We1, const float* __restrict__ be1,
    const float* __restrict__ We2, const float* __restrict__ be2,
    const float* __restrict__ mlp_scale, const float* __restrict__ log_bias,
    float* __restrict__ accum)
{
    __shared__ float xs[DEMB];
    __shared__ float part1[4 * WID];
    __shared__ float h0s[WID];
    __shared__ float part2[4 * WID];
    const int tid = threadIdx.x, wv = tid >> 6, lane = tid & 63;
    const int r = blockIdx.x;

    xs[tid] = emb[(r << 8) + tid];
    __syncthreads();

    // layer 1: wave wv covers k in [wv*64, wv*64+64), fully unrolled, 4 accums
    const int kb = wv << 6;
    float a0 = 0, a1 = 0, a2 = 0, a3 = 0;
    #pragma unroll
    for (int q = 0; q < 64; q += 4) {
        a0 = fmaf(xs[kb + q],     We0[(kb + q)     * WID + lane], a0);
        a1 = fmaf(xs[kb + q + 1], We0[(kb + q + 1) * WID + lane], a1);
        a2 = fmaf(xs[kb + q + 2], We0[(kb + q + 2) * WID + lane], a2);
        a3 = fmaf(xs[kb + q + 3], We0[(kb + q + 3) * WID + lane], a3);
    }
    part1[(wv << 6) + lane] = (a0 + a1) + (a2 + a3);
    __syncthreads();

    if (wv == 0) {
        const float s = part1[lane] + part1[64 + lane] + part1[128 + lane]
                      + part1[192 + lane] + be0[lane];
        h0s[lane] = tanh_pre(CTANH * s);
    }
    __syncthreads();

    // layer 2: wave wv covers k in [wv*16, wv*16+16)
    const int kb2 = wv << 4;
    float c0 = 0, c1 = 0;
    #pragma unroll
    for (int q = 0; q < 16; q += 2) {
        c0 = fmaf(h0s[kb2 + q],     We1[(kb2 + q)     * WID + lane], c0);
        c1 = fmaf(h0s[kb2 + q + 1], We1[(kb2 + q + 1) * WID + lane], c1);
    }
    part2[(wv << 6) + lane] = c0 + c1;
    __syncthreads();

    if (wv == 0) {
        const float c = part2[lane] + part2[64 + lane] + part2[128 + lane]
                      + part2[192 + lane] + be1[lane];
        const float h1 = tanh_pre(CTANH * c);
        float p0 = h1 * We2[2 * lane], p1 = h1 * We2[2 * lane + 1];
        #pragma unroll
        for (int off = 32; off; off >>= 1) {
            p0 += __shfl_down(p0, off);
            p1 += __shfl_down(p1, off);
        }
        if (lane == 0) {
            const int b = (r & 63) << 4;
            atomicAdd(&accum[1024 + b], (p0 + be2[0]) * mlp_scale[0]);
            atomicAdd(&accum[1032 + b], (p1 + be2[1]) * mlp_scale[1] + log_bias[0]);
        }
    }
}

__global__ __launch_bounds__(64) void final_kernel(const float* __restrict__ accum,
                                                   float* __restrict__ out)
{
    const int lane = threadIdx.x;
    float v  = accum[lane << 4];
    float j0 = accum[1024 + (lane << 4)];
    float j1 = accum[1032 + (lane << 4)];
    #pragma unroll
    for (int off = 32; off; off >>= 1) {
        v  += __shfl_down(v, off);
        j0 += __shfl_down(j0, off);
        j1 += __shfl_down(j1, off);
    }
    if (lane == 0) {
        const float sign = (j1 > 0.0f) ? 1.0f : ((j1 < 0.0f) ? -1.0f : 0.0f);
        out[0] = sign;
        out[1] = v + j0 + logf(fabsf(j1));
    }
}

extern "C" void kernel_launch(void* const* d_in, const int* in_sizes, int n_in,
                              void* d_out, int out_size, void* d_ws, size_t ws_size,
                              hipStream_t stream) {
    const float* electrons  = (const float*)d_in[0];
    const float* embeddings = (const float*)d_in[1];
    const float* A_same     = (const float*)d_in[2];
    const float* A_diff     = (const float*)d_in[3];
    const float* Ws0_same   = (const float*)d_in[4];
    const float* bs0_same   = (const float*)d_in[5];
    const float* Ws1_same   = (const float*)d_in[6];
    const float* bs1_same   = (const float*)d_in[7];
    const float* Ws2_same   = (const float*)d_in[8];
    const float* Ws0_diff   = (const float*)d_in[9];
    const float* bs0_diff   = (const float*)d_in[10];
    const float* Ws1_diff   = (const float*)d_in[11];
    const float* bs1_diff   = (const float*)d_in[12];
    const float* Ws2_diff   = (const float*)d_in[13];
    const float* scale_same = (const float*)d_in[14];
    const float* scale_diff = (const float*)d_in[15];
    const float* We0        = (const float*)d_in[16];
    const float* be0        = (const float*)d_in[17];
    const float* We1        = (const float*)d_in[18];
    const float* be1        = (const float*)d_in[19];
    const float* We2        = (const float*)d_in[20];
    const float* be2        = (const float*)d_in[21];
    const float* mlp_scale  = (const float*)d_in[22];
    const float* log_bias   = (const float*)d_in[23];

    float* out = (float*)d_out;
    float* wsf = (float*)d_ws;

    hipLaunchKernelGGL(prep_kernel, dim3(17), dim3(256), 0, stream,
        Ws0_same, bs0_same, Ws1_same, bs1_same, Ws2_same,
        Ws0_diff, bs0_diff, Ws1_diff, bs1_diff, Ws2_diff,
        A_same, A_diff, scale_same, scale_diff, wsf);

    hipLaunchKernelGGL(pair_kernel, dim3(NEL * NEL / 128), dim3(256), 0, stream,
        electrons, wsf, wsf);

    hipLaunchKernelGGL(embed_kernel, dim3(NEL), dim3(256), 0, stream,
        embeddings, We0, be0, We1, be1, We2, be2, mlp_scale, log_bias, wsf);

    hipLaunchKernelGGL(final_kernel, dim3(1), dim3(64), 0, stream, wsf, out);
}

// Round 10
// 49.865 us; speedup vs baseline: 16.0229x; 1.0446x over previous
//
#include <hip/hip_runtime.h>

#define NEL 1024
#define NUP 512
#define DEMB 256
#define WID 64

typedef __attribute__((ext_vector_type(4))) float f32x4;
typedef __attribute__((ext_vector_type(16))) float f32x16;
typedef __attribute__((ext_vector_type(4))) unsigned int u32x4;
typedef __attribute__((ext_vector_type(8))) _Float16 f16x8;
typedef __attribute__((ext_vector_type(2))) _Float16 h2;

#define CTANH 2.8853900817779268f   // 2*log2(e) (embed path only)
#define LOG2E 1.4426950408889634f
#define LN2   0.6931471805599453f

// ws float layout:
//  [0..1023]        : 64 cache-line buckets (stride 16): pair at +0, embJ0 at +4, embJ1 at +8
//  [1024 + s*512]   : per-set tables: b1[64] f32 | w2f f16[64] (frag-order, *scale) @+64
//                     | w0f f16[256] @+96 | b0f f16[64] @+224 | {A, log2e/F} @+256
//  [2048 ..]        : w1f: per-set 4096 f16 (frag-order), set stride 2048 floats

__device__ __forceinline__ float tanh_pre(float y) {   // embed path (y = CTANH*a)
    float e = __builtin_amdgcn_exp2f(y);
    return fmaf(-2.0f, __builtin_amdgcn_rcpf(e + 1.0f), 1.0f);
}

__device__ __forceinline__ float softplus_f(float x) {
    return fmaxf(x, 0.0f) + __logf(1.0f + __expf(-fabsf(x)));
}

__device__ __forceinline__ h2 h2s(float f) {
    _Float16 v = (_Float16)f; h2 r; r[0] = v; r[1] = v; return r;
}
__device__ __forceinline__ h2 bch2(unsigned u) { return __builtin_bit_cast(h2, u); }
__device__ __forceinline__ unsigned h2bits(h2 h) { return __builtin_bit_cast(unsigned, h); }

// tanh(x) ~= xc * P((xc/4)^2), xc = clamp(x,-4,4). deg-5 interpolant, |err|<~1.3e-2.
__device__ __forceinline__ h2 tanh2(h2 x) {
    x = __builtin_elementwise_min(h2s(4.0f), __builtin_elementwise_max(h2s(-4.0f), x));
    h2 xq = x * h2s(0.25f);
    h2 v  = xq * xq;
    h2 p  = h2s(-5.150581f);
    p = p * v + h2s(16.252870f);
    p = p * v + h2s(-19.909140f);
    p = p * v + h2s(12.125338f);
    p = p * v + h2s(-4.052176f);
    p = p * v + h2s(0.983638f);
    return x * p;
}

__global__ __launch_bounds__(256) void prep_kernel(
    const float* __restrict__ W0s, const float* __restrict__ b0s,
    const float* __restrict__ W1s, const float* __restrict__ b1s, const float* __restrict__ W2s,
    const float* __restrict__ W0d, const float* __restrict__ b0d,
    const float* __restrict__ W1d, const float* __restrict__ b1d, const float* __restrict__ W2d,
    const float* __restrict__ As, const float* __restrict__ Ad,
    const float* __restrict__ ss, const float* __restrict__ sd,
    float* __restrict__ wsf)
{
    const int b = blockIdx.x, tid = threadIdx.x;
    if (b < 16) {
        // W1 -> f16 fragment-order: per block (s, h, kc): 512 f16
        const int s = b >> 3, h = (b >> 2) & 1, kc = b & 3;
        const float* W1 = s ? W1d : W1s;
        _Float16* w1out = (_Float16*)(wsf + 2048) + s * 4096 + (h * 4 + kc) * 512;
        #pragma unroll
        for (int it = 0; it < 2; ++it) {
            const int id = tid + it * 256;       // id = l*8 + e
            const int l = id >> 3, e = id & 7;
            const int k = kc * 16 + (l >> 5) * 8 + e;
            const int n = h * 32 + (l & 31);
            w1out[id] = (_Float16)W1[k * 64 + n];
        }
    } else {
        for (int idx = tid; idx < 1024; idx += 256) wsf[idx] = 0.0f;
        #pragma unroll
        for (int s = 0; s < 2; ++s) {
            const float* W0 = s ? W0d : W0s;
            const float* b0 = s ? b0d : b0s;
            const float* b1 = s ? b1d : b1s;
            const float* w2 = s ? W2d : W2s;
            const float scl = (s ? sd : ss)[0];
            const int base = 1024 + s * 512;
            if (tid < 64) wsf[base + tid] = b1[tid];                    // b1 plain f32
            if (tid < 64) {                                             // w2f frag-order
                const int h = tid >> 5, hi = (tid >> 4) & 1, rp = (tid >> 1) & 7, wh = tid & 1;
                const int n = h * 32 + ((2 * rp) & 3) + 8 * (rp >> 1) + 4 * hi + wh;
                ((_Float16*)(wsf + base + 64))[tid] = (_Float16)(scl * w2[n]);
            }
            {                                                           // w0f packed pairs
                const int kc = tid >> 6, hi = (tid >> 5) & 1, ep = (tid >> 3) & 3;
                const int k = (tid >> 1) & 3, wh = tid & 1;
                const int n = kc * 16 + hi * 8 + 2 * ep + wh;
                ((_Float16*)(wsf + base + 96))[tid] = (_Float16)W0[k * 64 + n];
            }
            if (tid < 64) {                                             // b0f packed pairs
                const int kc = tid >> 4, hi = (tid >> 3) & 1, ep = (tid >> 1) & 3, wh = tid & 1;
                ((_Float16*)(wsf + base + 224))[tid] = (_Float16)b0[kc * 16 + hi * 8 + 2 * ep + wh];
            }
            if (tid == 0) {
                const float A = softplus_f((s ? Ad : As)[0]);
                wsf[base + 256] = A;
                wsf[base + 257] = LOG2E * __builtin_amdgcn_rsqf(2.0f * A);
            }
        }
    }
}

// 128 pairs per block (wave = 32 pairs). f16 packed L1 + poly-tanh + f16 MFMA,
// n-halves computed sequentially to keep register pressure low.
__global__ __launch_bounds__(256, 6) void pair_kernel(
    const float* __restrict__ electrons,
    const float* __restrict__ wsf,
    float* __restrict__ accum)
{
    __shared__ __align__(16) char smem[8592];
    char*  w1lds = smem;                      // 8192 B: f16 frag-order W1
    float* b1sh  = (float*)(smem + 8192);     // 64 f32
    char*  w2lds = smem + 8448;               // 128 B: f16 frag-order w2*scale
    float* wsum  = (float*)(smem + 8576);     // 4

    const int tid  = threadIdx.x;
    const int bidx = blockIdx.x;
    const int i  = bidx >> 3;
    const int jb = (bidx & 7) << 7;
    const int sset = ((i < NUP) == (jb < NUP)) ? 0 : 1;
    const float* tb = wsf + 1024 + sset * 512;

    // stage: W1 frags (512 float4), b1 (16), w2f (8)
    {
        const float4* src = (const float4*)(wsf + 2048 + sset * 2048);
        float4* dst = (float4*)w1lds;
        dst[tid]       = src[tid];
        dst[tid + 256] = src[tid + 256];
        if (tid < 16) ((float4*)b1sh)[tid] = ((const float4*)tb)[tid];
        if (tid < 8)  ((float4*)w2lds)[tid] = ((const float4*)(tb + 64))[tid];
    }
    const float A     = tb[256];
    const float invF2 = tb[257];

    const int lane = tid & 63, wv = tid >> 6;
    const int hi = lane >> 5, p32 = lane & 31;
    const int j = jb + (wv << 5) + p32;
    const bool diag = (j == i);

    // ---- features (f32, sanitized on diagonal) ----
    const float eix = electrons[3 * i], eiy = electrons[3 * i + 1], eiz = electrons[3 * i + 2];
    float dx = eix - electrons[3 * j];
    float dy = eiy - electrons[3 * j + 1];
    float dz = eiz - electrons[3 * j + 2];
    if (diag) { dx = 0.0f; dy = 0.0f; dz = 0.0f; }
    float r2 = fmaf(dx, dx, fmaf(dy, dy, dz * dz));
    if (diag) r2 = 1.0f;
    const float rr    = __builtin_amdgcn_sqrtf(r2);
    const float inv_r = __builtin_amdgcn_rcpf(rr);
    const float l1p   = __builtin_amdgcn_logf(1.0f + rr) * LN2;
    const float gf    = l1p * inv_r;
    const float cusp = (hi == 0 && !diag)
        ? A * (__builtin_amdgcn_exp2f(-rr * invF2) - 1.0f) * inv_r : 0.0f;

    const h2 fs0 = h2s(dx * gf);
    const h2 fs1 = h2s(dy * gf);
    const h2 fs2 = h2s(dz * gf);
    const h2 fs3 = h2s(diag ? 0.0f : l1p);

    __syncthreads();

    // ---- layer 1: packed f16, straight into B-fragment layout ----
    const char* w0g = (const char*)(tb + 96);    // f16[256]
    const char* b0g = (const char*)(tb + 224);   // f16[64]
    f16x8 afr[4];
    #pragma unroll
    for (int kc = 0; kc < 4; ++kc) {
        const u32x4 b0v = *(const u32x4*)(b0g + (((kc << 1) + hi) << 4));
        u32x4 frag;
        #pragma unroll
        for (int ep = 0; ep < 4; ++ep) {
            const u32x4 wv4 = *(const u32x4*)(w0g + (((kc << 1) + hi) << 6) + (ep << 4));
            h2 a = bch2(b0v[ep]);
            a = bch2(wv4[0]) * fs0 + a;
            a = bch2(wv4[1]) * fs1 + a;
            a = bch2(wv4[2]) * fs2 + a;
            a = bch2(wv4[3]) * fs3 + a;
            frag[ep] = h2bits(tanh2(a));
        }
        afr[kc] = __builtin_bit_cast(f16x8, frag);
    }

    // ---- layer 2 (f16 MFMA) + layer 3, n-halves sequential ----
    float ssum = 0.0f;
    #pragma unroll
    for (int h = 0; h < 2; ++h) {
        f32x16 acc;
        #pragma unroll
        for (int q = 0; q < 4; ++q) {
            const f32x4 bv = *(const f32x4*)(b1sh + (h << 5) + (q << 3) + (hi << 2));
            #pragma unroll
            for (int e = 0; e < 4; ++e) acc[(q << 2) + e] = bv[e];
        }
        #pragma unroll
        for (int kc = 0; kc < 4; ++kc) {
            const f16x8 wa = *(const f16x8*)(w1lds + ((((h << 2) + kc) << 6) + lane) * 16);
            acc = __builtin_amdgcn_mfma_f32_32x32x16_f16(wa, afr[kc], acc, 0, 0, 0);
        }
        const char* w2c = w2lds + (((h << 1) + hi) << 5);
        const u32x4 w2a = *(const u32x4*)(w2c);
        const u32x4 w2b = *(const u32x4*)(w2c + 16);
        h2 s2 = h2s(0.0f);
        #pragma unroll
        for (int q = 0; q < 4; ++q) {
            h2 p0; p0[0] = (_Float16)acc[(q << 2) + 0]; p0[1] = (_Float16)acc[(q << 2) + 1];
            h2 p1; p1[0] = (_Float16)acc[(q << 2) + 2]; p1[1] = (_Float16)acc[(q << 2) + 3];
            const h2 t0 = tanh2(p0);
            const h2 t1 = tanh2(p1);
            const unsigned wlo = (q < 2) ? w2a[(q << 1)]     : w2b[((q - 2) << 1)];
            const unsigned whi = (q < 2) ? w2a[(q << 1) + 1] : w2b[((q - 2) << 1) + 1];
            s2 = t0 * bch2(wlo) + s2;
            s2 = t1 * bch2(whi) + s2;
        }
        ssum += (float)s2[0] + (float)s2[1];
    }
    if (diag) ssum = 0.0f;
    float partial = ssum + cusp;

    #pragma unroll
    for (int off = 32; off; off >>= 1) partial += __shfl_down(partial, off);
    if (lane == 0) wsum[wv] = partial;
    __syncthreads();
    if (tid == 0)
        atomicAdd(&accum[(bidx & 63) << 4], wsum[0] + wsum[1] + wsum[2] + wsum[3]);
}

// One row per block, split-k across 4 waves.
__global__ __launch_bounds__(256) void embed_kernel(
    const float* __restrict__ emb,
    const float* __restrict__ We0, const float* __restrict__ be0,
    const float* __restrict__ We1, const float* __restrict__ be1,
    const float* __restrict__ We2, const float* __restrict__ be2,
    const float* __restrict__ mlp_scale, const float* __restrict__ log_bias,
    float* __restrict__ accum)
{
    __shared__ float xs[DEMB];
    __shared__ float part1[4 * WID];
    __shared__ float h0s[WID];
    __shared__ float part2[4 * WID];
    const int tid = threadIdx.x, wv = tid >> 6, lane = tid & 63;
    const int r = blockIdx.x;

    xs[tid] = emb[(r << 8) + tid];
    __syncthreads();

    const int kb = wv << 6;
    float a0 = 0, a1 = 0, a2 = 0, a3 = 0;
    #pragma unroll
    for (int q = 0; q < 64; q += 4) {
        a0 = fmaf(xs[kb + q],     We0[(kb + q)     * WID + lane], a0);
        a1 = fmaf(xs[kb + q + 1], We0[(kb + q + 1) * WID + lane], a1);
        a2 = fmaf(xs[kb + q + 2], We0[(kb + q + 2) * WID + lane], a2);
        a3 = fmaf(xs[kb + q + 3], We0[(kb + q + 3) * WID + lane], a3);
    }
    part1[(wv << 6) + lane] = (a0 + a1) + (a2 + a3);
    __syncthreads();

    if (wv == 0) {
        const float s = part1[lane] + part1[64 + lane] + part1[128 + lane]
                      + part1[192 + lane] + be0[lane];
        h0s[lane] = tanh_pre(CTANH * s);
    }
    __syncthreads();

    const int kb2 = wv << 4;
    float c0 = 0, c1 = 0;
    #pragma unroll
    for (int q = 0; q < 16; q += 2) {
        c0 = fmaf(h0s[kb2 + q],     We1[(kb2 + q)     * WID + lane], c0);
        c1 = fmaf(h0s[kb2 + q + 1], We1[(kb2 + q + 1) * WID + lane], c1);
    }
    part2[(wv << 6) + lane] = c0 + c1;
    __syncthreads();

    if (wv == 0) {
        const float c = part2[lane] + part2[64 + lane] + part2[128 + lane]
                      + part2[192 + lane] + be1[lane];
        const float h1 = tanh_pre(CTANH * c);
        float p0 = h1 * We2[2 * lane], p1 = h1 * We2[2 * lane + 1];
        #pragma unroll
        for (int off = 32; off; off >>= 1) {
            p0 += __shfl_down(p0, off);
            p1 += __shfl_down(p1, off);
        }
        if (lane == 0) {
            const int b = (r & 63) << 4;
            atomicAdd(&accum[b + 4], (p0 + be2[0]) * mlp_scale[0]);
            atomicAdd(&accum[b + 8], (p1 + be2[1]) * mlp_scale[1] + log_bias[0]);
        }
    }
}

__global__ __launch_bounds__(64) void final_kernel(const float* __restrict__ accum,
                                                   float* __restrict__ out)
{
    const int lane = threadIdx.x;
    float v  = accum[(lane << 4)];
    float j0 = accum[(lane << 4) + 4];
    float j1 = accum[(lane << 4) + 8];
    #pragma unroll
    for (int off = 32; off; off >>= 1) {
        v  += __shfl_down(v, off);
        j0 += __shfl_down(j0, off);
        j1 += __shfl_down(j1, off);
    }
    if (lane == 0) {
        const float sign = (j1 > 0.0f) ? 1.0f : ((j1 < 0.0f) ? -1.0f : 0.0f);
        out[0] = sign;
        out[1] = v + j0 + logf(fabsf(j1));
    }
}

extern "C" void kernel_launch(void* const* d_in, const int* in_sizes, int n_in,
                              void* d_out, int out_size, void* d_ws, size_t ws_size,
                              hipStream_t stream) {
    const float* electrons  = (const float*)d_in[0];
    const float* embeddings = (const float*)d_in[1];
    const float* A_same     = (const float*)d_in[2];
    const float* A_diff     = (const float*)d_in[3];
    const float* Ws0_same   = (const float*)d_in[4];
    const float* bs0_same   = (const float*)d_in[5];
    const float* Ws1_same   = (const float*)d_in[6];
    const float* bs1_same   = (const float*)d_in[7];
    const float* Ws2_same   = (const float*)d_in[8];
    const float* Ws0_diff   = (const float*)d_in[9];
    const float* bs0_diff   = (const float*)d_in[10];
    const float* bs1w_diff  = (const float*)d_in[11];
    const float* bs1_diff   = (const float*)d_in[12];
    const float* Ws2_diff   = (const float*)d_in[13];
    const float* scale_same = (const float*)d_in[14];
    const float* scale_diff = (const float*)d_in[15];
    const float* We0        = (const float*)d_in[16];
    const float* be0        = (const float*)d_in[17];
    const float* We1        = (const float*)d_in[18];
    const float* be1        = (const float*)d_in[19];
    const float* We2        = (const float*)d_in[20];
    const float* be2        = (const float*)d_in[21];
    const float* mlp_scale  = (const float*)d_in[22];
    const float* log_bias   = (const float*)d_in[23];

    float* out = (float*)d_out;
    float* wsf = (float*)d_ws;

    hipLaunchKernelGGL(prep_kernel, dim3(17), dim3(256), 0, stream,
        Ws0_same, bs0_same, Ws1_same, bs1_same, Ws2_same,
        Ws0_diff, bs0_diff, bs1w_diff, bs1_diff, Ws2_diff,
        A_same, A_diff, scale_same, scale_diff, wsf);

    hipLaunchKernelGGL(pair_kernel, dim3(NEL * NEL / 128), dim3(256), 0, stream,
        electrons, wsf, wsf);

    hipLaunchKernelGGL(embed_kernel, dim3(NEL), dim3(256), 0, stream,
        embeddings, We0, be0, We1, be1, We2, be2, mlp_scale, log_bias, wsf);

    hipLaunchKernelGGL(final_kernel, dim3(1), dim3(64), 0, stream, wsf, out);
}